// Round 1
// baseline (1234.313 us; speedup 1.0000x reference)
//
#include <hip/hip_runtime.h>
#include <hip/hip_bf16.h>

#define N_PTS 50000
#define NNB   32
#define KP    15
#define DIN   64
#define DOUT  1024
#define KDIM  (KP*DIN)    // 960
#define NB    16
#define SIGMA_INV (1.0f/0.3f)

#define TM 64
#define TN 64
#define TK 32
#define RB ((N_PTS + TM - 1)/TM)   // 782

static __device__ __forceinline__ float bf2f(unsigned short u) {
  union { unsigned int i; float f; } v; v.i = ((unsigned int)u) << 16; return v.f;
}

// ---------------- Kernel 1: build g[n, k*64+d] (bf16) -----------------------
// One block (256 thr) per point. h is ~always 0 (random neighbors, sigma=0.3),
// so we build a 32-bit "neighbor has any nonzero h" mask and only run the
// 64-wide FMA for active neighbors (~1 per point on average).
__global__ __launch_bounds__(256) void kpconv_g_kernel(
    const float* __restrict__ pos, const float* __restrict__ feats,
    const float* __restrict__ kpts, const int* __restrict__ nidx,
    __hip_bfloat16* __restrict__ g) {
  __shared__ float h_lds[NNB][16];
  __shared__ int   idx_lds[NNB];
  __shared__ unsigned int anymask;
  int n = blockIdx.x;
  int tid = threadIdx.x;
  if (tid == 0) anymask = 0u;
  if (tid < NNB) idx_lds[tid] = nidx[n*NNB + tid];
  __syncthreads();
  float px = pos[n*3+0], py = pos[n*3+1], pz = pos[n*3+2];
  for (int t = tid; t < NNB*16; t += 256) {
    int j = t >> 4, k = t & 15;
    float h = 0.0f;
    if (k < KP) {
      int id = idx_lds[j];
      float rx = pos[id*3+0] - px;
      float ry = pos[id*3+1] - py;
      float rz = pos[id*3+2] - pz;
      float dx = rx - kpts[k*3+0];
      float dy = ry - kpts[k*3+1];
      float dz = rz - kpts[k*3+2];
      float d = sqrtf(dx*dx + dy*dy + dz*dz);
      h = 1.0f - d * SIGMA_INV;
      h = h > 0.0f ? h : 0.0f;
      if (h > 0.0f) atomicOr(&anymask, 1u << j);
    }
    h_lds[j][k] = h;
  }
  __syncthreads();
  unsigned int mask = anymask;   // wave-uniform
  int wav  = tid >> 6;           // 0..3 : k-group
  int lane = tid & 63;           // d channel
  float acc0 = 0.f, acc1 = 0.f, acc2 = 0.f, acc3 = 0.f;
  while (mask) {
    int j = __ffs(mask) - 1;
    mask &= mask - 1;
    float f = feats[(size_t)idx_lds[j]*DIN + lane];
    acc0 += h_lds[j][wav+0]  * f;
    acc1 += h_lds[j][wav+4]  * f;
    acc2 += h_lds[j][wav+8]  * f;
    if (wav < 3) acc3 += h_lds[j][wav+12] * f;
  }
  size_t base = (size_t)n*KDIM;
  g[base + (wav+0)*DIN + lane]  = __float2bfloat16(acc0);
  g[base + (wav+4)*DIN + lane]  = __float2bfloat16(acc1);
  g[base + (wav+8)*DIN + lane]  = __float2bfloat16(acc2);
  if (wav < 3) g[base + (wav+12)*DIN + lane] = __float2bfloat16(acc3);
}

// ---------------- Kernel 2: GEMM [N,960]x[960,1024] + leaky + pool partials --
// f32 accumulate, A = g (bf16), B = kp_weights (f32). Tile 64x64, BK=32,
// 256 threads, 4x4 micro-tile. Epilogue: leaky_relu, then deterministic
// per-(row-block, batch-id) partial sums written to ws.
__global__ __launch_bounds__(256) void gemm_pool_kernel(
    const __hip_bfloat16* __restrict__ g, const float* __restrict__ W,
    const int* __restrict__ batch, float* __restrict__ partial) {
  __shared__ float smem[2*TK*68];          // As = smem[0..], Bs = smem + TK*68
  __shared__ float psum[NB][64];
  __shared__ int   bid[TM];
  float* As = smem;                        // [TK][68], As[kk][row]
  float* Bs = smem + TK*68;                // [TK][68], Bs[kk][col]
  int rb = blockIdx.y, cb = blockIdx.x;
  int r0 = rb*TM, c0 = cb*TN;
  int tid = threadIdx.x;
  int tx = tid & 15, ty = tid >> 4;
  float acc[4][4] = {};
  for (int k0 = 0; k0 < KDIM; k0 += TK) {
    #pragma unroll
    for (int p = 0; p < 2; ++p) {          // stage A: 64 rows x 32 k (bf16)
      int row = (tid >> 3) + p*32;
      int ch  = (tid & 7) * 4;
      int r   = r0 + row;
      float a0=0.f, a1=0.f, a2=0.f, a3=0.f;
      if (r < N_PTS) {
        const ushort4 v = *reinterpret_cast<const ushort4*>(&g[(size_t)r*KDIM + k0 + ch]);
        a0 = bf2f(v.x); a1 = bf2f(v.y); a2 = bf2f(v.z); a3 = bf2f(v.w);
      }
      As[(ch+0)*68+row] = a0; As[(ch+1)*68+row] = a1;
      As[(ch+2)*68+row] = a2; As[(ch+3)*68+row] = a3;
    }
    #pragma unroll
    for (int p = 0; p < 2; ++p) {          // stage B: 32 k x 64 cols (f32)
      int kk = (tid >> 4) + p*16;
      int cc = (tid & 15) * 4;
      const float4 w = *reinterpret_cast<const float4*>(&W[(size_t)(k0+kk)*DOUT + c0 + cc]);
      *reinterpret_cast<float4*>(&Bs[kk*68 + cc]) = w;
    }
    __syncthreads();
    #pragma unroll
    for (int kk = 0; kk < TK; ++kk) {
      float4 av = *reinterpret_cast<const float4*>(&As[kk*68 + ty*4]);
      float4 bv = *reinterpret_cast<const float4*>(&Bs[kk*68 + tx*4]);
      float a[4] = {av.x, av.y, av.z, av.w};
      float b[4] = {bv.x, bv.y, bv.z, bv.w};
      #pragma unroll
      for (int i = 0; i < 4; ++i)
        #pragma unroll
        for (int jj = 0; jj < 4; ++jj)
          acc[i][jj] += a[i] * b[jj];
    }
    __syncthreads();
  }
  // batch ids of this row block
  if (tid < TM) {
    int r = r0 + tid;
    bid[tid] = (r < N_PTS) ? (batch[r] & 15) : -1;
  }
  // leaky relu, stash tile in LDS (reuse smem as [64][68])
  #pragma unroll
  for (int i = 0; i < 4; ++i) {
    int rr = ty*4 + i;
    #pragma unroll
    for (int jj = 0; jj < 4; ++jj) {
      float v = acc[i][jj];
      v = v > 0.0f ? v : 0.1f*v;
      smem[rr*68 + tx*4 + jj] = v;
    }
  }
  for (int z = tid; z < NB*64; z += 256) (&psum[0][0])[z] = 0.0f;
  __syncthreads();
  // deterministic run-sum over the (sorted) batch ids, one thread per column
  if (tid < 64) {
    int c = tid;
    float s = 0.0f;
    int cur = bid[0];
    for (int r = 0; r < TM; ++r) {
      int b = bid[r];
      if (b != cur) { if (cur >= 0) psum[cur][c] = s; s = 0.0f; cur = b; }
      s += smem[r*68 + c];
    }
    if (cur >= 0) psum[cur][c] = s;
  }
  __syncthreads();
  for (int z = tid; z < NB*64; z += 256) {
    int b = z >> 6, c = z & 63;
    partial[((size_t)rb*NB + b)*DOUT + c0 + c] = psum[b][c];
  }
}

// ---------------- Kernel 3: reduce partials -> pooled mean -------------------
__global__ __launch_bounds__(256) void reduce_pool_kernel(
    const float* __restrict__ partial, const int* __restrict__ batch,
    float* __restrict__ pooled) {
  int b = blockIdx.y;
  int c = blockIdx.x*256 + threadIdx.x;
  float s0=0.f, s1=0.f, s2=0.f, s3=0.f;
  int rb = 0;
  for (; rb + 4 <= RB; rb += 4) {
    s0 += partial[((size_t)(rb+0)*NB + b)*DOUT + c];
    s1 += partial[((size_t)(rb+1)*NB + b)*DOUT + c];
    s2 += partial[((size_t)(rb+2)*NB + b)*DOUT + c];
    s3 += partial[((size_t)(rb+3)*NB + b)*DOUT + c];
  }
  for (; rb < RB; ++rb) s0 += partial[((size_t)rb*NB + b)*DOUT + c];
  float s = (s0+s1)+(s2+s3);
  int lb, ub;
  { int l = 0, r = N_PTS; while (l < r) { int m = (l+r)>>1; if (batch[m] <  b) l = m+1; else r = m; } lb = l; }
  { int l = 0, r = N_PTS; while (l < r) { int m = (l+r)>>1; if (batch[m] <= b) l = m+1; else r = m; } ub = l; }
  float cnt = (float)(ub - lb);
  pooled[b*DOUT + c] = s / fmaxf(cnt, 1.0f);
}

// ---------------- MLP head ---------------------------------------------------
__global__ __launch_bounds__(512) void mlp1_kernel(const float* __restrict__ pooled,
    const float* __restrict__ w1, const float* __restrict__ b1, float* __restrict__ h1) {
  __shared__ float pl[DOUT];
  int b = blockIdx.x, o = threadIdx.x;
  for (int i = o; i < DOUT; i += 512) pl[i] = pooled[b*DOUT + i];
  __syncthreads();
  float acc = b1[o];
  #pragma unroll 8
  for (int i = 0; i < DOUT; ++i) acc += pl[i] * w1[(size_t)i*512 + o];
  h1[b*512 + o] = fmaxf(acc, 0.0f);
}

__global__ __launch_bounds__(256) void mlp2_kernel(const float* __restrict__ h1,
    const float* __restrict__ w2, const float* __restrict__ b2, float* __restrict__ h2) {
  __shared__ float hl[512];
  int b = blockIdx.x, o = threadIdx.x;
  for (int i = o; i < 512; i += 256) hl[i] = h1[b*512 + i];
  __syncthreads();
  float acc = b2[o];
  #pragma unroll 8
  for (int i = 0; i < 512; ++i) acc += hl[i] * w2[(size_t)i*256 + o];
  h2[b*256 + o] = fmaxf(acc, 0.0f);
}

__global__ __launch_bounds__(192) void mlp3_kernel(const float* __restrict__ h2,
    const float* __restrict__ w3, const float* __restrict__ b3, float* __restrict__ out) {
  __shared__ float hl[256];
  int b = blockIdx.x, o = threadIdx.x;
  for (int i = o; i < 256; i += 192) hl[i] = h2[b*256 + i];
  __syncthreads();
  if (o < 152) {
    float acc = b3[o];
    #pragma unroll 8
    for (int i = 0; i < 256; ++i) acc += hl[i] * w3[i*152 + o];
    out[b*152 + o] = acc;
  }
}

// ---------------- launch -----------------------------------------------------
extern "C" void kernel_launch(void* const* d_in, const int* in_sizes, int n_in,
                              void* d_out, int out_size, void* d_ws, size_t ws_size,
                              hipStream_t stream) {
  (void)in_sizes; (void)n_in; (void)out_size; (void)ws_size;
  const float* pos   = (const float*)d_in[0];
  const float* feats = (const float*)d_in[1];
  const float* kpts  = (const float*)d_in[2];
  const float* kpw   = (const float*)d_in[3];
  const float* w1    = (const float*)d_in[4];
  const float* b1    = (const float*)d_in[5];
  const float* w2    = (const float*)d_in[6];
  const float* b2    = (const float*)d_in[7];
  const float* w3    = (const float*)d_in[8];
  const float* b3    = (const float*)d_in[9];
  const int* nidx    = (const int*)d_in[10];
  const int* batch   = (const int*)d_in[11];
  float* out = (float*)d_out;

  char* ws = (char*)d_ws;
  const size_t off_g       = 0;                       // 50000*960*2   = 96,000,000
  const size_t off_partial = 96000000;                // 782*16*1024*4 = 51,249,152
  const size_t off_pooled  = off_partial + 51249152;  // 65,536
  const size_t off_h1      = off_pooled + 65536;      // 32,768
  const size_t off_h2      = off_h1 + 32768;          // 16,384
  __hip_bfloat16* g = (__hip_bfloat16*)(ws + off_g);
  float* partial = (float*)(ws + off_partial);
  float* pooled  = (float*)(ws + off_pooled);
  float* h1      = (float*)(ws + off_h1);
  float* h2      = (float*)(ws + off_h2);

  kpconv_g_kernel<<<N_PTS, 256, 0, stream>>>(pos, feats, kpts, nidx, g);
  gemm_pool_kernel<<<dim3(DOUT/TN, RB), 256, 0, stream>>>(g, kpw, batch, partial);
  reduce_pool_kernel<<<dim3(DOUT/256, NB), 256, 0, stream>>>(partial, batch, pooled);
  mlp1_kernel<<<NB, 512, 0, stream>>>(pooled, w1, b1, h1);
  mlp2_kernel<<<NB, 256, 0, stream>>>(h1, w2, b2, h2);
  mlp3_kernel<<<NB, 192, 0, stream>>>(h2, w3, b3, out);
}

// Round 2
// 376.839 us; speedup vs baseline: 3.2754x; 3.2754x over previous
//
#include <hip/hip_runtime.h>
#include <hip/hip_bf16.h>

#define N_PTS 50000
#define NNB   32
#define KP    15
#define DIN   64
#define DOUT  1024
#define KDIM  (KP*DIN)    // 960
#define NB    16
#define SIGMA_INV (1.0f/0.3f)

#define BM 128
#define BN 128
#define BK 32
#define RB ((N_PTS + BM - 1)/BM)   // 391 row blocks
#define M_PAD (RB*BM)              // 50048

typedef __attribute__((ext_vector_type(8))) short bf16x8;
typedef __attribute__((ext_vector_type(4))) float f32x4;

#define GLD16(gsrc, ldst) \
  __builtin_amdgcn_global_load_lds((const __attribute__((address_space(1))) char*)(gsrc), \
                                   (__attribute__((address_space(3))) char*)(ldst), 16, 0, 0)

static __device__ __forceinline__ float bf2f(unsigned short u) {
  union { unsigned int i; float f; } v; v.i = ((unsigned int)u) << 16; return v.f;
}

// ---------------- Kernel 0: W [960][1024] f32 -> Wt [1024][960] bf16 ---------
__global__ __launch_bounds__(256) void wt_kernel(
    const float* __restrict__ W, __hip_bfloat16* __restrict__ Wt) {
  __shared__ float t[64][65];
  int k0 = blockIdx.x * 64;   // 15
  int o0 = blockIdx.y * 64;   // 16
  int tx = threadIdx.x & 63, ty = threadIdx.x >> 6;
  for (int r = ty; r < 64; r += 4) t[r][tx] = W[(size_t)(k0 + r)*DOUT + o0 + tx];
  __syncthreads();
  for (int r = ty; r < 64; r += 4)
    Wt[(size_t)(o0 + r)*KDIM + k0 + tx] = __float2bfloat16(t[tx][r]);
}

// ---------------- Kernel 1: build g[n, k*64+d] (bf16), padded to M_PAD ------
__global__ __launch_bounds__(256) void kpconv_g_kernel(
    const float* __restrict__ pos, const float* __restrict__ feats,
    const float* __restrict__ kpts, const int* __restrict__ nidx,
    __hip_bfloat16* __restrict__ g) {
  int n = blockIdx.x;
  int tid = threadIdx.x;
  if (n >= N_PTS) {   // pad rows: zero
    size_t base = (size_t)n*KDIM;
    for (int t = tid; t < KDIM; t += 256) g[base + t] = __float2bfloat16(0.0f);
    return;
  }
  __shared__ float h_lds[NNB][16];
  __shared__ int   idx_lds[NNB];
  __shared__ unsigned int anymask;
  if (tid == 0) anymask = 0u;
  if (tid < NNB) idx_lds[tid] = nidx[n*NNB + tid];
  __syncthreads();
  float px = pos[n*3+0], py = pos[n*3+1], pz = pos[n*3+2];
  for (int t = tid; t < NNB*16; t += 256) {
    int j = t >> 4, k = t & 15;
    float h = 0.0f;
    if (k < KP) {
      int id = idx_lds[j];
      float rx = pos[id*3+0] - px;
      float ry = pos[id*3+1] - py;
      float rz = pos[id*3+2] - pz;
      float dx = rx - kpts[k*3+0];
      float dy = ry - kpts[k*3+1];
      float dz = rz - kpts[k*3+2];
      float d = sqrtf(dx*dx + dy*dy + dz*dz);
      h = 1.0f - d * SIGMA_INV;
      h = h > 0.0f ? h : 0.0f;
      if (h > 0.0f) atomicOr(&anymask, 1u << j);
    }
    h_lds[j][k] = h;
  }
  __syncthreads();
  unsigned int mask = anymask;   // wave-uniform
  int wav  = tid >> 6;           // 0..3 : k-group
  int lane = tid & 63;           // d channel
  float acc0 = 0.f, acc1 = 0.f, acc2 = 0.f, acc3 = 0.f;
  while (mask) {
    int j = __ffs(mask) - 1;
    mask &= mask - 1;
    float f = feats[(size_t)idx_lds[j]*DIN + lane];
    acc0 += h_lds[j][wav+0]  * f;
    acc1 += h_lds[j][wav+4]  * f;
    acc2 += h_lds[j][wav+8]  * f;
    if (wav < 3) acc3 += h_lds[j][wav+12] * f;
  }
  size_t base = (size_t)n*KDIM;
  g[base + (wav+0)*DIN + lane]  = __float2bfloat16(acc0);
  g[base + (wav+4)*DIN + lane]  = __float2bfloat16(acc1);
  g[base + (wav+8)*DIN + lane]  = __float2bfloat16(acc2);
  if (wav < 3) g[base + (wav+12)*DIN + lane] = __float2bfloat16(acc3);
}

// ---------------- Kernel 2: MFMA GEMM [M_PAD,960]x[960,1024]^T + pool --------
// A = g (bf16, row-major K), B = Wt (bf16, [N][K]). m97 structure: 128x128
// tile, BK=32, 4 waves 2x2, 16x16x32 MFMA. LDS slot-swizzled (2-way = free).
// Epilogue: leaky_relu + deterministic per-batch partial sums.
__global__ __launch_bounds__(256) void gemm_mfma_pool(
    const __hip_bfloat16* __restrict__ g, const __hip_bfloat16* __restrict__ Wt,
    const int* __restrict__ batch, float* __restrict__ partial) {
  __shared__ __align__(16) char lA[BM*64];   // 8KB, row*64B + slot*16B
  __shared__ __align__(16) char lB[BN*64];   // 8KB
  __shared__ float psum[NB][BN];
  __shared__ int bid[BM];
  int rb = blockIdx.y, cb = blockIdx.x;
  int r0 = rb*BM, c0 = cb*BN;
  int tid = threadIdx.x;
  int lane = tid & 63, w = tid >> 6;
  int wr = w >> 1, wc = w & 1;

  f32x4 acc[4][4] = {};   // acc[m][n]

  for (int k0 = 0; k0 < KDIM; k0 += BK) {
    #pragma unroll
    for (int p = 0; p < 2; ++p) {
      int i = p*256 + tid;
      int row = i >> 2, slot = i & 3;
      int kg = slot ^ ((row >> 1) & 3);          // inverse-swizzled global source
      GLD16(g  + (size_t)(r0+row)*KDIM + k0 + kg*8, lA + i*16);
      GLD16(Wt + (size_t)(c0+row)*KDIM + k0 + kg*8, lB + i*16);
    }
    __syncthreads();
    bf16x8 af[4], bfr[4];
    #pragma unroll
    for (int m = 0; m < 4; ++m) {
      int row = wr*64 + m*16 + (lane & 15);
      int slot = (lane >> 4) ^ ((row >> 1) & 3);  // swizzled read
      af[m] = *(const bf16x8*)(lA + row*64 + slot*16);
    }
    #pragma unroll
    for (int n = 0; n < 4; ++n) {
      int row = wc*64 + n*16 + (lane & 15);
      int slot = (lane >> 4) ^ ((row >> 1) & 3);
      bfr[n] = *(const bf16x8*)(lB + row*64 + slot*16);
    }
    #pragma unroll
    for (int m = 0; m < 4; ++m)
      #pragma unroll
      for (int n = 0; n < 4; ++n)
        acc[m][n] = __builtin_amdgcn_mfma_f32_16x16x32_bf16(af[m], bfr[n], acc[m][n], 0, 0, 0);
    __syncthreads();
  }

  // ---- epilogue: leaky + deterministic per-batch column sums ----
  if (tid < BM) bid[tid] = (r0 + tid < N_PTS) ? batch[r0 + tid] : -1;
  for (int z = tid; z < NB*BN; z += 256) (&psum[0][0])[z] = 0.0f;
  __syncthreads();
  int rquad = lane >> 4;
  #pragma unroll 1
  for (int phase = 0; phase < 8; ++phase) {
    if (wr*4 + rquad == phase) {
      #pragma unroll
      for (int n = 0; n < 4; ++n) {
        int c = wc*64 + n*16 + (lane & 15);
        float run = 0.0f; int curb = -2;
        #pragma unroll
        for (int m = 0; m < 4; ++m) {
          #pragma unroll
          for (int j = 0; j < 4; ++j) {
            int r = wr*64 + m*16 + rquad*4 + j;
            int b = bid[r];
            float v = acc[m][n][j];
            v = v > 0.0f ? v : 0.1f*v;
            if (b != curb) { if (curb >= 0) psum[curb][c] += run; run = 0.0f; curb = b; }
            run += v;
          }
        }
        if (curb >= 0) psum[curb][c] += run;
      }
    }
    __syncthreads();
  }
  for (int z = tid; z < NB*BN; z += 256) {
    int b = z >> 7, c = z & 127;
    partial[((size_t)rb*NB + b)*DOUT + c0 + c] = psum[b][c];
  }
}

// ---------------- Kernel 3: reduce partials -> pooled mean -------------------
__global__ __launch_bounds__(256) void reduce_pool_kernel(
    const float* __restrict__ partial, const int* __restrict__ batch,
    float* __restrict__ pooled) {
  int b = blockIdx.y;
  int c = blockIdx.x*256 + threadIdx.x;
  float s0=0.f, s1=0.f, s2=0.f, s3=0.f;
  int rb = 0;
  for (; rb + 4 <= RB; rb += 4) {
    s0 += partial[((size_t)(rb+0)*NB + b)*DOUT + c];
    s1 += partial[((size_t)(rb+1)*NB + b)*DOUT + c];
    s2 += partial[((size_t)(rb+2)*NB + b)*DOUT + c];
    s3 += partial[((size_t)(rb+3)*NB + b)*DOUT + c];
  }
  for (; rb < RB; ++rb) s0 += partial[((size_t)rb*NB + b)*DOUT + c];
  float s = (s0+s1)+(s2+s3);
  int lb, ub;
  { int l = 0, r = N_PTS; while (l < r) { int m = (l+r)>>1; if (batch[m] <  b) l = m+1; else r = m; } lb = l; }
  { int l = 0, r = N_PTS; while (l < r) { int m = (l+r)>>1; if (batch[m] <= b) l = m+1; else r = m; } ub = l; }
  float cnt = (float)(ub - lb);
  pooled[b*DOUT + c] = s / fmaxf(cnt, 1.0f);
}

// ---------------- MLP head ---------------------------------------------------
__global__ __launch_bounds__(512) void mlp1_kernel(const float* __restrict__ pooled,
    const float* __restrict__ w1, const float* __restrict__ b1, float* __restrict__ h1) {
  __shared__ float pl[DOUT];
  int b = blockIdx.x, o = threadIdx.x;
  for (int i = o; i < DOUT; i += 512) pl[i] = pooled[b*DOUT + i];
  __syncthreads();
  float acc = b1[o];
  #pragma unroll 8
  for (int i = 0; i < DOUT; ++i) acc += pl[i] * w1[(size_t)i*512 + o];
  h1[b*512 + o] = fmaxf(acc, 0.0f);
}

__global__ __launch_bounds__(256) void mlp2_kernel(const float* __restrict__ h1,
    const float* __restrict__ w2, const float* __restrict__ b2, float* __restrict__ h2) {
  __shared__ float hl[512];
  int b = blockIdx.x, o = threadIdx.x;
  for (int i = o; i < 512; i += 256) hl[i] = h1[b*512 + i];
  __syncthreads();
  float acc = b2[o];
  #pragma unroll 8
  for (int i = 0; i < 512; ++i) acc += hl[i] * w2[(size_t)i*256 + o];
  h2[b*256 + o] = fmaxf(acc, 0.0f);
}

__global__ __launch_bounds__(192) void mlp3_kernel(const float* __restrict__ h2,
    const float* __restrict__ w3, const float* __restrict__ b3, float* __restrict__ out) {
  __shared__ float hl[256];
  int b = blockIdx.x, o = threadIdx.x;
  for (int i = o; i < 256; i += 192) hl[i] = h2[b*256 + i];
  __syncthreads();
  if (o < 152) {
    float acc = b3[o];
    #pragma unroll 8
    for (int i = 0; i < 256; ++i) acc += hl[i] * w3[i*152 + o];
    out[b*152 + o] = acc;
  }
}

// ---------------- launch -----------------------------------------------------
extern "C" void kernel_launch(void* const* d_in, const int* in_sizes, int n_in,
                              void* d_out, int out_size, void* d_ws, size_t ws_size,
                              hipStream_t stream) {
  (void)in_sizes; (void)n_in; (void)out_size; (void)ws_size;
  const float* pos   = (const float*)d_in[0];
  const float* feats = (const float*)d_in[1];
  const float* kpts  = (const float*)d_in[2];
  const float* kpw   = (const float*)d_in[3];
  const float* w1    = (const float*)d_in[4];
  const float* b1    = (const float*)d_in[5];
  const float* w2    = (const float*)d_in[6];
  const float* b2    = (const float*)d_in[7];
  const float* w3    = (const float*)d_in[8];
  const float* b3    = (const float*)d_in[9];
  const int* nidx    = (const int*)d_in[10];
  const int* batch   = (const int*)d_in[11];
  float* out = (float*)d_out;

  char* ws = (char*)d_ws;
  const size_t off_g       = 0;                          // 50048*960*2   = 96,092,160
  const size_t off_wt      = 96092160;                   // 1024*960*2    = 1,966,080
  const size_t off_partial = off_wt + 1966080;           // 391*16*1024*4 = 25,624,576
  const size_t off_pooled  = off_partial + 25624576;
  const size_t off_h1      = off_pooled + 65536;
  const size_t off_h2      = off_h1 + 32768;
  __hip_bfloat16* g  = (__hip_bfloat16*)(ws + off_g);
  __hip_bfloat16* wt = (__hip_bfloat16*)(ws + off_wt);
  float* partial = (float*)(ws + off_partial);
  float* pooled  = (float*)(ws + off_pooled);
  float* h1      = (float*)(ws + off_h1);
  float* h2      = (float*)(ws + off_h2);

  wt_kernel<<<dim3(KDIM/64, DOUT/64), 256, 0, stream>>>(kpw, wt);
  kpconv_g_kernel<<<M_PAD, 256, 0, stream>>>(pos, feats, kpts, nidx, g);
  gemm_mfma_pool<<<dim3(DOUT/BN, RB), 256, 0, stream>>>(g, wt, batch, partial);
  reduce_pool_kernel<<<dim3(DOUT/256, NB), 256, 0, stream>>>(partial, batch, pooled);
  mlp1_kernel<<<NB, 512, 0, stream>>>(pooled, w1, b1, h1);
  mlp2_kernel<<<NB, 256, 0, stream>>>(h1, w2, b2, h2);
  mlp3_kernel<<<NB, 192, 0, stream>>>(h2, w3, b3, out);
}